// Round 5
// baseline (279.179 us; speedup 1.0000x reference)
//
#include <hip/hip_runtime.h>

// Performer causal linear attention, MI355X. Round 5:
//  - feat: P staged in LDS (4 quarters, double-buffered) -> ds_read B-frags;
//    diag via shuffle on fp32 staging regs; epilogue LDS aliased over X+Pbuf0.
// b=2 h=8 n=4096 d=64 r=256 e=64, chunk=64.

typedef unsigned short ushort_t;
typedef __attribute__((ext_vector_type(8))) short bf16x8;
typedef __attribute__((ext_vector_type(4))) float f32x4;

#define KEPS 1e-4f
#define AEPS 1e-6f
#define NORMIZER 0.35355339059327373f   // 64^-0.25
#define RATIO 0.0625f                   // 256^-0.5

__device__ __forceinline__ unsigned fenc(float f) {
  unsigned u = __float_as_uint(f);
  return (u & 0x80000000u) ? ~u : (u | 0x80000000u);
}
__device__ __forceinline__ float fdec(unsigned e) {
  unsigned u = (e & 0x80000000u) ? (e ^ 0x80000000u) : ~e;
  return __uint_as_float(u);
}
__device__ __forceinline__ ushort_t bf16r(float f) {   // RNE
  unsigned u = __float_as_uint(f);
  return (ushort_t)((u + 0x7fffu + ((u >> 16) & 1u)) >> 16);
}
__device__ __forceinline__ float ubf(ushort_t h) {
  return __uint_as_float((unsigned)h << 16);
}

// ---------------------------------------------------------------------------
// K0: split P into bf16 hi/lo.
__global__ __launch_bounds__(256) void pconv_kernel(
    const float* __restrict__ P, ushort_t* __restrict__ Phi,
    ushort_t* __restrict__ Plo)
{
  int idx = blockIdx.x * 1024 + threadIdx.x;
  #pragma unroll
  for (int p = 0; p < 4; ++p) {
    int i = idx + p * 256;
    float x = P[i];
    ushort_t h = bf16r(x);
    Phi[i] = h;
    Plo[i] = bf16r(x - ubf(h));
  }
}

// ---------------------------------------------------------------------------
// K1: feature map via MFMA, P double-buffered through LDS.
// blocks 0..1023 -> q, 1024..2047 -> k. 64 rows x 256 cols per block.
__global__ __launch_bounds__(256) void feat_mfma(
    const float* __restrict__ Q, const float* __restrict__ K,
    const ushort_t* __restrict__ Phi, const ushort_t* __restrict__ Plo,
    ushort_t* __restrict__ qp, ushort_t* __restrict__ E,
    unsigned int* __restrict__ kmax)
{
  __shared__ union {
    struct {
      ushort_t Xhi[64 * 72];        //  9216 B
      ushort_t Xlo[64 * 72];        //  9216 B
      ushort_t Pb[2][2][64 * 68];   // 34816 B  [buf][hi/lo][col*68 + k]
    } s;
    ushort_t outb[64 * 264];        // 33792 B  (aliases X + Pb[0], never Pb[1])
  } u;
  __shared__ float diagS[64];
  __shared__ float redm[4];

  int bid = blockIdx.x, tid = threadIdx.x;
  bool isK = bid >= 1024;
  const float* X = isK ? K : Q;
  size_t rowbase = (size_t)(isK ? bid - 1024 : bid) * 64;

  // stage X -> hi/lo bf16; diag from the fp32 regs via 16-lane shuffle reduce
  #pragma unroll
  for (int p = 0; p < 4; ++p) {
    int idx = tid + p * 256;
    int row = idx >> 4, c4 = idx & 15;
    float4 x = *(const float4*)&X[(rowbase + row) * 64 + c4 * 4];
    ushort4 h, l;
    h.x = bf16r(x.x); l.x = bf16r(x.x - ubf(h.x));
    h.y = bf16r(x.y); l.y = bf16r(x.y - ubf(h.y));
    h.z = bf16r(x.z); l.z = bf16r(x.z - ubf(h.z));
    h.w = bf16r(x.w); l.w = bf16r(x.w - ubf(h.w));
    *(ushort4*)&u.s.Xhi[row * 72 + c4 * 4] = h;
    *(ushort4*)&u.s.Xlo[row * 72 + c4 * 4] = l;
    float ss = x.x * x.x + x.y * x.y + x.z * x.z + x.w * x.w;
    ss += __shfl_xor(ss, 1, 64); ss += __shfl_xor(ss, 2, 64);
    ss += __shfl_xor(ss, 4, 64); ss += __shfl_xor(ss, 8, 64);
    if ((tid & 15) == 0) diagS[row] = 0.0625f * ss;
  }
  // stage P quarter 0 into Pb[0]
  #pragma unroll
  for (int t = 0; t < 2; ++t) {
    int f = tid + t * 256;
    int cl = f >> 3, k8 = (f & 7) * 8;
    *(bf16x8*)&u.s.Pb[0][0][cl * 68 + k8] = *(const bf16x8*)&Phi[(size_t)cl * 64 + k8];
    *(bf16x8*)&u.s.Pb[0][1][cl * 68 + k8] = *(const bf16x8*)&Plo[(size_t)cl * 64 + k8];
  }
  __syncthreads();

  int lane = tid & 63, wv = tid >> 6;
  int n15 = lane & 15, quad = lane >> 4;

  // A-fragments (hi/lo) — read once, before any LDS aliasing
  bf16x8 ah[2], al[2];
  #pragma unroll
  for (int ks = 0; ks < 2; ++ks) {
    int off = (16 * wv + n15) * 72 + quad * 8 + 32 * ks;
    ah[ks] = *(const bf16x8*)&u.s.Xhi[off];
    al[ks] = *(const bf16x8*)&u.s.Xlo[off];
  }

  f32x4 acc[16];
  #pragma unroll
  for (int tc = 0; tc < 16; ++tc) acc[tc] = f32x4{0.f, 0.f, 0.f, 0.f};

  #pragma unroll
  for (int q = 0; q < 4; ++q) {
    // prefetch next quarter into regs (overlaps with this quarter's MFMAs)
    bf16x8 ph[2], pl[2];
    if (q < 3) {
      #pragma unroll
      for (int t = 0; t < 2; ++t) {
        int f = tid + t * 256;
        int cl = f >> 3, k8 = (f & 7) * 8;
        ph[t] = *(const bf16x8*)&Phi[(size_t)((q + 1) * 64 + cl) * 64 + k8];
        pl[t] = *(const bf16x8*)&Plo[(size_t)((q + 1) * 64 + cl) * 64 + k8];
      }
    }
    const ushort_t* Ph = u.s.Pb[q & 1][0];
    const ushort_t* Pl = u.s.Pb[q & 1][1];
    #pragma unroll
    for (int tcl = 0; tcl < 4; ++tcl) {
      f32x4 a = acc[q * 4 + tcl];
      #pragma unroll
      for (int ks = 0; ks < 2; ++ks) {
        int off = (16 * tcl + n15) * 68 + quad * 8 + 32 * ks;
        bf16x8 bh = *(const bf16x8*)&Ph[off];
        bf16x8 bl = *(const bf16x8*)&Pl[off];
        a = __builtin_amdgcn_mfma_f32_16x16x32_bf16(ah[ks], bh, a, 0, 0, 0);
        a = __builtin_amdgcn_mfma_f32_16x16x32_bf16(ah[ks], bl, a, 0, 0, 0);
        a = __builtin_amdgcn_mfma_f32_16x16x32_bf16(al[ks], bh, a, 0, 0, 0);
      }
      acc[q * 4 + tcl] = a;
    }
    if (q < 3) {
      #pragma unroll
      for (int t = 0; t < 2; ++t) {
        int f = tid + t * 256;
        int cl = f >> 3, k8 = (f & 7) * 8;
        *(bf16x8*)&u.s.Pb[(q + 1) & 1][0][cl * 68 + k8] = ph[t];
        *(bf16x8*)&u.s.Pb[(q + 1) & 1][1][cl * 68 + k8] = pl[t];
      }
      __syncthreads();
    }
  }

  // C/D: row = 16*wv + quad*4 + r, col = 16*tc + n15
  float dg[4];
  #pragma unroll
  for (int r = 0; r < 4; ++r) dg[r] = diagS[16 * wv + quad * 4 + r];

  if (!isK) {
    float mx[4] = {-3.0e38f, -3.0e38f, -3.0e38f, -3.0e38f};
    #pragma unroll
    for (int tc = 0; tc < 16; ++tc)
      #pragma unroll
      for (int r = 0; r < 4; ++r) mx[r] = fmaxf(mx[r], acc[tc][r]);
    #pragma unroll
    for (int r = 0; r < 4; ++r) {
      #pragma unroll
      for (int s = 1; s < 16; s <<= 1) mx[r] = fmaxf(mx[r], __shfl_xor(mx[r], s, 64));
    }
    #pragma unroll
    for (int r = 0; r < 4; ++r) {
      int row = 16 * wv + quad * 4 + r;
      float sub = dg[r] + NORMIZER * mx[r];
      #pragma unroll
      for (int tc = 0; tc < 16; ++tc)
        u.outb[row * 264 + 16 * tc + n15] =
            bf16r(RATIO * (__expf(NORMIZER * acc[tc][r] - sub) + KEPS));
    }
  } else {
    float bm = -3.0e38f;
    #pragma unroll
    for (int r = 0; r < 4; ++r) {
      int row = 16 * wv + quad * 4 + r;
      #pragma unroll
      for (int tc = 0; tc < 16; ++tc) {
        float d = acc[tc][r];
        bm = fmaxf(bm, d);
        u.outb[row * 264 + 16 * tc + n15] = bf16r(__expf(NORMIZER * d - dg[r]));
      }
    }
    #pragma unroll
    for (int s = 1; s < 64; s <<= 1) bm = fmaxf(bm, __shfl_xor(bm, s, 64));
    if (lane == 0) redm[wv] = bm;
  }
  __syncthreads();

  // coalesced 16B stores
  ushort_t* dst = (isK ? E : qp) + rowbase * 256;
  #pragma unroll
  for (int p = 0; p < 8; ++p) {
    int f = p * 2048 + tid * 8;
    int row = f >> 8, col = f & 255;
    bf16x8 vv = *(const bf16x8*)&u.outb[row * 264 + col];
    *(bf16x8*)&dst[row * 256 + col] = vv;
  }

  if (isK && tid == 0) {
    float m4 = fmaxf(fmaxf(redm[0], redm[1]), fmaxf(redm[2], redm[3]));
    atomicMax(kmax, fenc(NORMIZER * m4));
  }
}

// ---------------------------------------------------------------------------
// K2: per-chunk sums. kp = c1*E + c0. S layout [bc][e][j].
__global__ __launch_bounds__(256) void chunksum_kernel(
    const ushort_t* __restrict__ E, const float* __restrict__ V,
    const unsigned int* __restrict__ kmax,
    ushort_t* __restrict__ S, float* __restrict__ Z)
{
  __shared__ float vs[4096];
  int bc = blockIdx.x, tid = threadIdx.x;
  float m = fdec(*kmax);
  float c1 = RATIO * __expf(-m);
  const float c0 = RATIO * KEPS;
  size_t vbase = (size_t)bc * 4096;
  #pragma unroll
  for (int p = 0; p < 16; ++p) vs[tid + p * 256] = V[vbase + tid + p * 256];
  __syncthreads();

  size_t kbase = (size_t)bc * 16384;
  float acc[64];
  #pragma unroll
  for (int e = 0; e < 64; ++e) acc[e] = 0.f;
  float z = 0.f;

  for (int pos = 0; pos < 64; ++pos) {
    float kj = c1 * ubf(E[kbase + (size_t)pos * 256 + tid]) + c0;
    z += kj;
    #pragma unroll
    for (int e4 = 0; e4 < 16; ++e4) {
      float4 vv = *(const float4*)&vs[pos * 64 + e4 * 4];
      acc[e4 * 4 + 0] += kj * vv.x;
      acc[e4 * 4 + 1] += kj * vv.y;
      acc[e4 * 4 + 2] += kj * vv.z;
      acc[e4 * 4 + 3] += kj * vv.w;
    }
  }
  #pragma unroll
  for (int e = 0; e < 64; ++e)
    S[kbase + (size_t)e * 256 + tid] = bf16r(acc[e]);
  Z[(size_t)bc * 256 + tid] = z;
}

// ---------------------------------------------------------------------------
// K3: exclusive prefix over 64 chunks per bh, in place. 8-deep prefetch.
__global__ __launch_bounds__(256) void prefix_kernel(ushort_t* __restrict__ S,
                                                     float* __restrict__ Z)
{
  int b = blockIdx.x;
  if (b < 1024) {
    int flat = b * 256 + threadIdx.x;
    int bh = flat >> 14;
    int idx = flat & 16383;
    size_t base = (size_t)bh * 1048576 + idx;
    float run = 0.f;
    for (int c0 = 0; c0 < 64; c0 += 8) {
      ushort_t t[8];
      #pragma unroll
      for (int u2 = 0; u2 < 8; ++u2)
        t[u2] = S[base + (size_t)(c0 + u2) * 16384];
      #pragma unroll
      for (int u2 = 0; u2 < 8; ++u2) {
        S[base + (size_t)(c0 + u2) * 16384] = bf16r(run);
        run += ubf(t[u2]);
      }
    }
  } else {
    int bh = b - 1024;
    int j = threadIdx.x;
    size_t base = (size_t)bh * 16384 + j;
    float run = 0.f;
    for (int c0 = 0; c0 < 64; c0 += 8) {
      float t[8];
      #pragma unroll
      for (int u2 = 0; u2 < 8; ++u2)
        t[u2] = Z[base + (size_t)(c0 + u2) * 256];
      #pragma unroll
      for (int u2 = 0; u2 < 8; ++u2) {
        Z[base + (size_t)(c0 + u2) * 256] = run;
        run += t[u2];
      }
    }
  }
}

// ---------------------------------------------------------------------------
// K4: fused MFMA scores + denominator + output. block = (bh,c).
__global__ __launch_bounds__(256) void fused_mfma(
    const ushort_t* __restrict__ qp, const ushort_t* __restrict__ E,
    const unsigned int* __restrict__ kmax, const float* __restrict__ Z,
    const ushort_t* __restrict__ S, const float* __restrict__ V,
    float* __restrict__ out)
{
  __shared__ ushort_t As[64 * 72];   // A_sc bf16, A-operand layout [i][t]
  __shared__ ushort_t Vt[64 * 72];   // V^T bf16 [e][t]
  __shared__ float zv[256];
  __shared__ float qsumS[64];
  __shared__ float dqS[64];

  int bc = blockIdx.x, tid = threadIdx.x;
  int lane = tid & 63, wv = tid >> 6;
  int n15 = lane & 15, quad = lane >> 4;
  float m = fdec(*kmax);
  float c1 = RATIO * __expf(-m);
  const float c0 = RATIO * KEPS;
  size_t base = (size_t)bc * 16384;

  zv[tid] = Z[(size_t)bc * 256 + tid] + AEPS;
  #pragma unroll
  for (int p = 0; p < 16; ++p) {
    int idx = tid + p * 256;
    int t = idx >> 6, e = idx & 63;
    Vt[e * 72 + t] = bf16r(V[(size_t)bc * 4096 + idx]);
  }
  __syncthreads();

  // Qp A-fragments: rows 16*wv + n15, held for both GEMMs
  bf16x8 aQ[8];
  #pragma unroll
  for (int ks = 0; ks < 8; ++ks)
    aQ[ks] = *(const bf16x8*)&qp[base + (size_t)(16 * wv + n15) * 256 + quad * 8 + 32 * ks];

  float qsum = 0.f, dq = 0.f;
  #pragma unroll
  for (int ks = 0; ks < 8; ++ks)
    #pragma unroll
    for (int j = 0; j < 8; ++j) {
      float qv = ubf((ushort_t)aQ[ks][j]);
      qsum += qv;
      dq += qv * zv[quad * 8 + 32 * ks + j];
    }
  qsum += __shfl_xor(qsum, 16, 64); qsum += __shfl_xor(qsum, 32, 64);
  dq   += __shfl_xor(dq, 16, 64);   dq   += __shfl_xor(dq, 32, 64);
  if (quad == 0) { qsumS[16 * wv + n15] = qsum; dqS[16 * wv + n15] = dq; }

  // ---- phase A: G = Qp * E^T ----
  float rs[4] = {0.f, 0.f, 0.f, 0.f};
  #pragma unroll
  for (int tc = 0; tc < 4; ++tc) {
    f32x4 g = {0.f, 0.f, 0.f, 0.f};
    #pragma unroll
    for (int ks = 0; ks < 8; ++ks) {
      bf16x8 b = *(const bf16x8*)&E[base + (size_t)(16 * tc + n15) * 256 + quad * 8 + 32 * ks];
      g = __builtin_amdgcn_mfma_f32_16x16x32_bf16(aQ[ks], b, g, 0, 0, 0);
    }
    #pragma unroll
    for (int r = 0; r < 4; ++r) {
      int i = 16 * wv + quad * 4 + r;
      int t = 16 * tc + n15;
      float val = (t <= i) ? (c1 * g[r] + c0 * qsumS[i]) : 0.f;
      As[i * 72 + t] = bf16r(val);
      rs[r] += val;
    }
  }

  float dinv[4];
  #pragma unroll
  for (int r = 0; r < 4; ++r) {
    float v = rs[r];
    #pragma unroll
    for (int s = 1; s < 16; s <<= 1) v += __shfl_xor(v, s, 64);
    int i = 16 * wv + quad * 4 + r;
    dinv[r] = 1.f / (dqS[i] + v);
  }

  // ---- phase C: out = [Qp | A_sc] * [Sp ; Vt] ----
  #pragma unroll
  for (int ec = 0; ec < 4; ++ec) {
    f32x4 o = {0.f, 0.f, 0.f, 0.f};
    #pragma unroll
    for (int ks = 0; ks < 8; ++ks) {
      bf16x8 b = *(const bf16x8*)&S[base + (size_t)(16 * ec + n15) * 256 + quad * 8 + 32 * ks];
      o = __builtin_amdgcn_mfma_f32_16x16x32_bf16(aQ[ks], b, o, 0, 0, 0);
    }
    #pragma unroll
    for (int ks = 0; ks < 2; ++ks) {
      bf16x8 a2 = *(const bf16x8*)&As[(16 * wv + n15) * 72 + quad * 8 + 32 * ks];
      bf16x8 b2 = *(const bf16x8*)&Vt[(16 * ec + n15) * 72 + quad * 8 + 32 * ks];
      o = __builtin_amdgcn_mfma_f32_16x16x32_bf16(a2, b2, o, 0, 0, 0);
    }
    #pragma unroll
    for (int r = 0; r < 4; ++r) {
      int i = 16 * wv + quad * 4 + r;
      out[(size_t)bc * 4096 + (size_t)i * 64 + 16 * ec + n15] = o[r] * dinv[r];
    }
  }
}

// ---------------------------------------------------------------------------
extern "C" void kernel_launch(void* const* d_in, const int* in_sizes, int n_in,
                              void* d_out, int out_size, void* d_ws, size_t ws_size,
                              hipStream_t stream)
{
  const float* q = (const float*)d_in[0];
  const float* k = (const float*)d_in[1];
  const float* v = (const float*)d_in[2];
  const float* P = (const float*)d_in[3];
  float* out = (float*)d_out;

  ushort_t* qp  = (ushort_t*)d_ws;
  ushort_t* E   = qp + 16777216;
  ushort_t* S   = E + 16777216;
  float*    Z   = (float*)(S + 16777216);
  ushort_t* Phi = (ushort_t*)(Z + 262144);
  ushort_t* Plo = Phi + 16384;
  unsigned int* kmax = (unsigned int*)(Plo + 16384);

  hipMemsetAsync(kmax, 0, 4, stream);
  pconv_kernel<<<16, 256, 0, stream>>>(P, Phi, Plo);
  feat_mfma<<<2048, 256, 0, stream>>>(q, k, Phi, Plo, qp, E, kmax);
  chunksum_kernel<<<1024, 256, 0, stream>>>(E, v, kmax, S, Z);
  prefix_kernel<<<1040, 256, 0, stream>>>(S, Z);
  fused_mfma<<<1024, 256, 0, stream>>>(qp, E, kmax, Z, S, v, out);
}

// Round 6
// 250.936 us; speedup vs baseline: 1.1126x; 1.1126x over previous
//
#include <hip/hip_runtime.h>

// Performer causal linear attention, MI355X. Round 6:
//  - feat: depth-1 B-frag register prefetch + per-quarter epilogue staging
//    (LDS 27.9 KB -> ~5 blocks/CU), __launch_bounds__(256,4)
//  - chunksum: MFMA rewrite, kmax-independent (SE/zE/SV unscaled)
//  - prefix: applies affine kp correction (c1,c0) while prefixing
// b=2 h=8 n=4096 d=64 r=256 e=64, chunk=64.

typedef unsigned short ushort_t;
typedef __attribute__((ext_vector_type(8))) short bf16x8;
typedef __attribute__((ext_vector_type(4))) float f32x4;

#define KEPS 1e-4f
#define AEPS 1e-6f
#define NORMIZER 0.35355339059327373f   // 64^-0.25
#define RATIO 0.0625f                   // 256^-0.5

__device__ __forceinline__ unsigned fenc(float f) {
  unsigned u = __float_as_uint(f);
  return (u & 0x80000000u) ? ~u : (u | 0x80000000u);
}
__device__ __forceinline__ float fdec(unsigned e) {
  unsigned u = (e & 0x80000000u) ? (e ^ 0x80000000u) : ~e;
  return __uint_as_float(u);
}
__device__ __forceinline__ ushort_t bf16r(float f) {   // RNE
  unsigned u = __float_as_uint(f);
  return (ushort_t)((u + 0x7fffu + ((u >> 16) & 1u)) >> 16);
}
__device__ __forceinline__ float ubf(ushort_t h) {
  return __uint_as_float((unsigned)h << 16);
}

// ---------------------------------------------------------------------------
// K0: split P into bf16 hi/lo.
__global__ __launch_bounds__(256) void pconv_kernel(
    const float* __restrict__ P, ushort_t* __restrict__ Phi,
    ushort_t* __restrict__ Plo)
{
  int idx = blockIdx.x * 1024 + threadIdx.x;
  #pragma unroll
  for (int p = 0; p < 4; ++p) {
    int i = idx + p * 256;
    float x = P[i];
    ushort_t h = bf16r(x);
    Phi[i] = h;
    Plo[i] = bf16r(x - ubf(h));
  }
}

// ---------------------------------------------------------------------------
// K1: feature map via MFMA. blocks 0..1023 -> q, 1024..2047 -> k.
__global__ __launch_bounds__(256, 4) void feat_mfma(
    const float* __restrict__ Q, const float* __restrict__ K,
    const ushort_t* __restrict__ Phi, const ushort_t* __restrict__ Plo,
    ushort_t* __restrict__ qp, ushort_t* __restrict__ E,
    unsigned int* __restrict__ kmax)
{
  __shared__ ushort_t Xhi[64 * 72];   // 9216 B
  __shared__ ushort_t Xlo[64 * 72];   // 9216 B
  __shared__ ushort_t outq[64 * 72];  // 9216 B per-quarter epilogue staging
  __shared__ float diagS[64];
  __shared__ float redm[4];

  int bid = blockIdx.x, tid = threadIdx.x;
  bool isK = bid >= 1024;
  const float* X = isK ? K : Q;
  size_t rowbase = (size_t)(isK ? bid - 1024 : bid) * 64;

  // stage X -> hi/lo bf16; diag via 16-lane shuffle reduce on fp32 regs
  #pragma unroll
  for (int p = 0; p < 4; ++p) {
    int idx = tid + p * 256;
    int row = idx >> 4, c4 = idx & 15;
    float4 x = *(const float4*)&X[(rowbase + row) * 64 + c4 * 4];
    ushort4 h, l;
    h.x = bf16r(x.x); l.x = bf16r(x.x - ubf(h.x));
    h.y = bf16r(x.y); l.y = bf16r(x.y - ubf(h.y));
    h.z = bf16r(x.z); l.z = bf16r(x.z - ubf(h.z));
    h.w = bf16r(x.w); l.w = bf16r(x.w - ubf(h.w));
    *(ushort4*)&Xhi[row * 72 + c4 * 4] = h;
    *(ushort4*)&Xlo[row * 72 + c4 * 4] = l;
    float ss = x.x * x.x + x.y * x.y + x.z * x.z + x.w * x.w;
    ss += __shfl_xor(ss, 1, 64); ss += __shfl_xor(ss, 2, 64);
    ss += __shfl_xor(ss, 4, 64); ss += __shfl_xor(ss, 8, 64);
    if ((tid & 15) == 0) diagS[row] = 0.0625f * ss;
  }
  __syncthreads();

  int lane = tid & 63, wv = tid >> 6;
  int n15 = lane & 15, quad = lane >> 4;

  bf16x8 ah[2], al[2];
  #pragma unroll
  for (int ks = 0; ks < 2; ++ks) {
    int off = (16 * wv + n15) * 72 + quad * 8 + 32 * ks;
    ah[ks] = *(const bf16x8*)&Xhi[off];
    al[ks] = *(const bf16x8*)&Xlo[off];
  }

  // MFMA loop with depth-1 register prefetch of B-fragments
  bf16x8 nbh[2], nbl[2];
  #pragma unroll
  for (int ks = 0; ks < 2; ++ks) {
    int poff = n15 * 64 + quad * 8 + 32 * ks;
    nbh[ks] = *(const bf16x8*)&Phi[poff];
    nbl[ks] = *(const bf16x8*)&Plo[poff];
  }

  f32x4 acc[16];
  #pragma unroll
  for (int tc = 0; tc < 16; ++tc) acc[tc] = f32x4{0.f, 0.f, 0.f, 0.f};

  #pragma unroll
  for (int tc = 0; tc < 16; ++tc) {
    bf16x8 bh0 = nbh[0], bl0 = nbl[0], bh1 = nbh[1], bl1 = nbl[1];
    if (tc < 15) {
      #pragma unroll
      for (int ks = 0; ks < 2; ++ks) {
        int poff = (16 * (tc + 1) + n15) * 64 + quad * 8 + 32 * ks;
        nbh[ks] = *(const bf16x8*)&Phi[poff];
        nbl[ks] = *(const bf16x8*)&Plo[poff];
      }
    }
    f32x4 a = acc[tc];
    a = __builtin_amdgcn_mfma_f32_16x16x32_bf16(ah[0], bh0, a, 0, 0, 0);
    a = __builtin_amdgcn_mfma_f32_16x16x32_bf16(ah[0], bl0, a, 0, 0, 0);
    a = __builtin_amdgcn_mfma_f32_16x16x32_bf16(al[0], bh0, a, 0, 0, 0);
    a = __builtin_amdgcn_mfma_f32_16x16x32_bf16(ah[1], bh1, a, 0, 0, 0);
    a = __builtin_amdgcn_mfma_f32_16x16x32_bf16(ah[1], bl1, a, 0, 0, 0);
    a = __builtin_amdgcn_mfma_f32_16x16x32_bf16(al[1], bh1, a, 0, 0, 0);
    acc[tc] = a;
  }

  // C/D: row = 16*wv + quad*4 + r, col = 16*tc + n15
  float dg[4];
  #pragma unroll
  for (int r = 0; r < 4; ++r) dg[r] = diagS[16 * wv + quad * 4 + r];

  float sub[4];
  if (!isK) {
    #pragma unroll
    for (int r = 0; r < 4; ++r) {
      float mx = -3.0e38f;
      #pragma unroll
      for (int tc = 0; tc < 16; ++tc) mx = fmaxf(mx, acc[tc][r]);
      #pragma unroll
      for (int s = 1; s < 16; s <<= 1) mx = fmaxf(mx, __shfl_xor(mx, s, 64));
      sub[r] = dg[r] + NORMIZER * mx;
    }
  } else {
    float bm = -3.0e38f;
    #pragma unroll
    for (int tc = 0; tc < 16; ++tc)
      #pragma unroll
      for (int r = 0; r < 4; ++r) bm = fmaxf(bm, acc[tc][r]);
    #pragma unroll
    for (int s = 1; s < 64; s <<= 1) bm = fmaxf(bm, __shfl_xor(bm, s, 64));
    if (lane == 0) redm[wv] = bm;
    #pragma unroll
    for (int r = 0; r < 4; ++r) sub[r] = dg[r];
  }

  // per-quarter epilogue: stage 64x64 in LDS, store coalesced
  ushort_t* dst = (isK ? E : qp) + rowbase * 256;
  #pragma unroll
  for (int qt = 0; qt < 4; ++qt) {
    if (qt) __syncthreads();
    #pragma unroll
    for (int t4 = 0; t4 < 4; ++t4) {
      int tc = qt * 4 + t4;
      #pragma unroll
      for (int r = 0; r < 4; ++r) {
        int row = 16 * wv + quad * 4 + r;
        float ex = __expf(NORMIZER * acc[tc][r] - sub[r]);
        float val = isK ? ex : RATIO * (ex + KEPS);
        outq[row * 72 + t4 * 16 + n15] = bf16r(val);
      }
    }
    __syncthreads();
    int row = tid >> 2, c0 = (tid & 3) * 16;
    bf16x8 v0 = *(const bf16x8*)&outq[row * 72 + c0];
    bf16x8 v1 = *(const bf16x8*)&outq[row * 72 + c0 + 8];
    *(bf16x8*)&dst[row * 256 + qt * 64 + c0] = v0;
    *(bf16x8*)&dst[row * 256 + qt * 64 + c0 + 8] = v1;
  }

  if (isK && tid == 0) {
    float m4 = fmaxf(fmaxf(redm[0], redm[1]), fmaxf(redm[2], redm[3]));
    atomicMax(kmax, fenc(NORMIZER * m4));
  }
}

// ---------------------------------------------------------------------------
// K2: per-chunk sums via MFMA, kmax-independent.
// SE[bc][e][j] = sum_pos E[pos][j] * v[pos][e]; zE[bc][j] = sum_pos E[pos][j];
// SV[bc][e] = sum_pos v[pos][e].
// LDS rows store pos rotated by 8*((row>>3)&7) to spread banks; reads
// compensate, so true-k alignment across lanes is preserved.
__global__ __launch_bounds__(256) void chunksum_mfma(
    const ushort_t* __restrict__ E, const float* __restrict__ V,
    ushort_t* __restrict__ SE, float* __restrict__ zE, float* __restrict__ SV)
{
  __shared__ ushort_t Et[256 * 72];   // 36864 B [j][pos-rot]
  __shared__ ushort_t Vt[64 * 72];    //  9216 B [e][pos-rot]
  __shared__ float red2[256];

  int bc = blockIdx.x, tid = threadIdx.x;
  size_t ebase = (size_t)bc * 16384;

  // stage E transposed
  #pragma unroll
  for (int p = 0; p < 8; ++p) {
    int g = (tid + p * 256) * 8;
    int pos = g >> 8, j0 = g & 255;
    bf16x8 ev = *(const bf16x8*)&E[ebase + g];
    #pragma unroll
    for (int jj = 0; jj < 8; ++jj) {
      int j = j0 + jj;
      int pr = (pos + 8 * ((j >> 3) & 7)) & 63;
      Et[j * 72 + pr] = (ushort_t)ev[jj];
    }
  }
  // stage V transposed + column partial sums
  float vsum = 0.f;
  #pragma unroll
  for (int p = 0; p < 16; ++p) {
    int g = tid + p * 256;
    int pos = g >> 6, e = g & 63;
    float x = V[(size_t)bc * 4096 + g];
    vsum += x;
    int pr = (pos + 8 * ((e >> 3) & 7)) & 63;
    Vt[e * 72 + pr] = bf16r(x);
  }
  red2[tid] = vsum;   // tid = grp*64 + e
  __syncthreads();
  if (tid < 64)
    SV[(size_t)bc * 64 + tid] =
        red2[tid] + red2[64 + tid] + red2[128 + tid] + red2[192 + tid];

  // zE: thread j sums its Et row (rotation is a permutation -> sum invariant)
  {
    float s = 0.f;
    #pragma unroll
    for (int m8 = 0; m8 < 8; ++m8) {
      bf16x8 r8 = *(const bf16x8*)&Et[tid * 72 + m8 * 8];
      #pragma unroll
      for (int x = 0; x < 8; ++x) s += ubf((ushort_t)r8[x]);
    }
    zE[(size_t)bc * 256 + tid] = s;
  }

  int lane = tid & 63, wv = tid >> 6;
  int n15 = lane & 15, quad = lane >> 4;

  // A-frags from Vt: row e = 16*wv + n15
  bf16x8 aV[2];
  {
    int e = 16 * wv + n15;
    int rot = 8 * ((e >> 3) & 7);
    #pragma unroll
    for (int ks = 0; ks < 2; ++ks) {
      int pr = (quad * 8 + 32 * ks + rot) & 63;
      aV[ks] = *(const bf16x8*)&Vt[e * 72 + pr];
    }
  }

  f32x4 acc[16];
  #pragma unroll
  for (int tc = 0; tc < 16; ++tc) {
    int j = 16 * tc + n15;
    int rot = 8 * ((j >> 3) & 7);
    f32x4 a = {0.f, 0.f, 0.f, 0.f};
    #pragma unroll
    for (int ks = 0; ks < 2; ++ks) {
      int pr = (quad * 8 + 32 * ks + rot) & 63;
      bf16x8 b = *(const bf16x8*)&Et[j * 72 + pr];
      a = __builtin_amdgcn_mfma_f32_16x16x32_bf16(aV[ks], b, a, 0, 0, 0);
    }
    acc[tc] = a;
  }
  __syncthreads();

  // epilogue: stage D [e][j] (pitch 264) aliased over Et, store coalesced
  ushort_t* outS = Et;   // 64*264 = 16896 ushorts <= 256*72 = 18432
  #pragma unroll
  for (int tc = 0; tc < 16; ++tc)
    #pragma unroll
    for (int r = 0; r < 4; ++r) {
      int e = 16 * wv + quad * 4 + r;
      outS[e * 264 + 16 * tc + n15] = bf16r(acc[tc][r]);
    }
  __syncthreads();
  #pragma unroll
  for (int p = 0; p < 8; ++p) {
    int g = (tid + p * 256) * 8;
    int e = g >> 8, j0 = g & 255;
    bf16x8 vv = *(const bf16x8*)&outS[e * 264 + j0];
    *(bf16x8*)&SE[ebase + g] = vv;
  }
}

// ---------------------------------------------------------------------------
// K3: exclusive prefix over 64 chunks per bh, applying kp affine correction.
// S[a] = c1*prefix(SE) + c0*prefix(SV);  z = prefix(c1*zE + 64*c0).
__global__ __launch_bounds__(256) void prefix_kernel(
    ushort_t* __restrict__ S, float* __restrict__ zE,
    const float* __restrict__ SV, const unsigned int* __restrict__ kmax)
{
  int b = blockIdx.x;
  float m = fdec(*kmax);
  float c1 = RATIO * __expf(-m);
  const float c0 = RATIO * KEPS;
  if (b < 1024) {
    int flat = b * 256 + threadIdx.x;
    int bh = flat >> 14;
    int idx = flat & 16383;
    int e = idx >> 8;                 // uniform per block
    size_t base = (size_t)bh * 1048576 + idx;
    const float* svp = SV + (size_t)bh * 4096 + e;   // step 64 per chunk
    float runE = 0.f, runV = 0.f;
    for (int cc = 0; cc < 64; cc += 8) {
      ushort_t t[8]; float sv[8];
      #pragma unroll
      for (int u2 = 0; u2 < 8; ++u2) {
        t[u2] = S[base + (size_t)(cc + u2) * 16384];
        sv[u2] = svp[(size_t)(cc + u2) * 64];
      }
      #pragma unroll
      for (int u2 = 0; u2 < 8; ++u2) {
        S[base + (size_t)(cc + u2) * 16384] = bf16r(c1 * runE + c0 * runV);
        runE += ubf(t[u2]);
        runV += sv[u2];
      }
    }
  } else {
    int bh = b - 1024;
    int j = threadIdx.x;
    size_t base = (size_t)bh * 16384 + j;
    float run = 0.f;
    for (int cc = 0; cc < 64; cc += 8) {
      float t[8];
      #pragma unroll
      for (int u2 = 0; u2 < 8; ++u2)
        t[u2] = zE[base + (size_t)(cc + u2) * 256];
      #pragma unroll
      for (int u2 = 0; u2 < 8; ++u2) {
        zE[base + (size_t)(cc + u2) * 256] = run;
        run += c1 * t[u2] + 64.0f * c0;
      }
    }
  }
}

// ---------------------------------------------------------------------------
// K4: fused MFMA scores + denominator + output. block = (bh,c).
__global__ __launch_bounds__(256) void fused_mfma(
    const ushort_t* __restrict__ qp, const ushort_t* __restrict__ E,
    const unsigned int* __restrict__ kmax, const float* __restrict__ Z,
    const ushort_t* __restrict__ S, const float* __restrict__ V,
    float* __restrict__ out)
{
  __shared__ ushort_t As[64 * 72];
  __shared__ ushort_t Vt[64 * 72];
  __shared__ float zv[256];
  __shared__ float qsumS[64];
  __shared__ float dqS[64];

  int bc = blockIdx.x, tid = threadIdx.x;
  int lane = tid & 63, wv = tid >> 6;
  int n15 = lane & 15, quad = lane >> 4;
  float m = fdec(*kmax);
  float c1 = RATIO * __expf(-m);
  const float c0 = RATIO * KEPS;
  size_t base = (size_t)bc * 16384;

  zv[tid] = Z[(size_t)bc * 256 + tid] + AEPS;
  #pragma unroll
  for (int p = 0; p < 16; ++p) {
    int idx = tid + p * 256;
    int t = idx >> 6, e = idx & 63;
    Vt[e * 72 + t] = bf16r(V[(size_t)bc * 4096 + idx]);
  }
  __syncthreads();

  bf16x8 aQ[8];
  #pragma unroll
  for (int ks = 0; ks < 8; ++ks)
    aQ[ks] = *(const bf16x8*)&qp[base + (size_t)(16 * wv + n15) * 256 + quad * 8 + 32 * ks];

  float qsum = 0.f, dq = 0.f;
  #pragma unroll
  for (int ks = 0; ks < 8; ++ks)
    #pragma unroll
    for (int j = 0; j < 8; ++j) {
      float qv = ubf((ushort_t)aQ[ks][j]);
      qsum += qv;
      dq += qv * zv[quad * 8 + 32 * ks + j];
    }
  qsum += __shfl_xor(qsum, 16, 64); qsum += __shfl_xor(qsum, 32, 64);
  dq   += __shfl_xor(dq, 16, 64);   dq   += __shfl_xor(dq, 32, 64);
  if (quad == 0) { qsumS[16 * wv + n15] = qsum; dqS[16 * wv + n15] = dq; }

  // ---- phase A: G = Qp * E^T ----
  float rs[4] = {0.f, 0.f, 0.f, 0.f};
  #pragma unroll
  for (int tc = 0; tc < 4; ++tc) {
    f32x4 g = {0.f, 0.f, 0.f, 0.f};
    #pragma unroll
    for (int ks = 0; ks < 8; ++ks) {
      bf16x8 b = *(const bf16x8*)&E[base + (size_t)(16 * tc + n15) * 256 + quad * 8 + 32 * ks];
      g = __builtin_amdgcn_mfma_f32_16x16x32_bf16(aQ[ks], b, g, 0, 0, 0);
    }
    #pragma unroll
    for (int r = 0; r < 4; ++r) {
      int i = 16 * wv + quad * 4 + r;
      int t = 16 * tc + n15;
      float val = (t <= i) ? (c1 * g[r] + c0 * qsumS[i]) : 0.f;
      As[i * 72 + t] = bf16r(val);
      rs[r] += val;
    }
  }

  float dinv[4];
  #pragma unroll
  for (int r = 0; r < 4; ++r) {
    float v = rs[r];
    #pragma unroll
    for (int s = 1; s < 16; s <<= 1) v += __shfl_xor(v, s, 64);
    int i = 16 * wv + quad * 4 + r;
    dinv[r] = 1.f / (dqS[i] + v);
  }

  // ---- phase C: out = [Qp | A_sc] * [Sp ; Vt] ----
  #pragma unroll
  for (int ec = 0; ec < 4; ++ec) {
    f32x4 o = {0.f, 0.f, 0.f, 0.f};
    #pragma unroll
    for (int ks = 0; ks < 8; ++ks) {
      bf16x8 b = *(const bf16x8*)&S[base + (size_t)(16 * ec + n15) * 256 + quad * 8 + 32 * ks];
      o = __builtin_amdgcn_mfma_f32_16x16x32_bf16(aQ[ks], b, o, 0, 0, 0);
    }
    #pragma unroll
    for (int ks = 0; ks < 2; ++ks) {
      bf16x8 a2 = *(const bf16x8*)&As[(16 * wv + n15) * 72 + quad * 8 + 32 * ks];
      bf16x8 b2 = *(const bf16x8*)&Vt[(16 * ec + n15) * 72 + quad * 8 + 32 * ks];
      o = __builtin_amdgcn_mfma_f32_16x16x32_bf16(a2, b2, o, 0, 0, 0);
    }
    #pragma unroll
    for (int r = 0; r < 4; ++r) {
      int i = 16 * wv + quad * 4 + r;
      out[(size_t)bc * 4096 + (size_t)i * 64 + 16 * ec + n15] = o[r] * dinv[r];
    }
  }
}

// ---------------------------------------------------------------------------
extern "C" void kernel_launch(void* const* d_in, const int* in_sizes, int n_in,
                              void* d_out, int out_size, void* d_ws, size_t ws_size,
                              hipStream_t stream)
{
  const float* q = (const float*)d_in[0];
  const float* k = (const float*)d_in[1];
  const float* v = (const float*)d_in[2];
  const float* P = (const float*)d_in[3];
  float* out = (float*)d_out;

  ushort_t* qp  = (ushort_t*)d_ws;
  ushort_t* E   = qp + 16777216;
  ushort_t* S   = E + 16777216;                 // SE then combined in place
  float*    zE  = (float*)(S + 16777216);       // 262144 floats
  float*    SV  = zE + 262144;                  // 65536 floats
  ushort_t* Phi = (ushort_t*)(SV + 65536);
  ushort_t* Plo = Phi + 16384;
  unsigned int* kmax = (unsigned int*)(Plo + 16384);

  hipMemsetAsync(kmax, 0, 4, stream);
  pconv_kernel<<<16, 256, 0, stream>>>(P, Phi, Plo);
  feat_mfma<<<2048, 256, 0, stream>>>(q, k, Phi, Plo, qp, E, kmax);
  chunksum_mfma<<<1024, 256, 0, stream>>>(E, v, S, zE, SV);
  prefix_kernel<<<1040, 256, 0, stream>>>(S, zE, SV, kmax);
  fused_mfma<<<1024, 256, 0, stream>>>(qp, E, kmax, zE, S, v, out);
}

// Round 7
// 228.648 us; speedup vs baseline: 1.2210x; 1.0975x over previous
//
#include <hip/hip_runtime.h>

// Performer causal linear attention, MI355X. Round 7:
//  - feat: global atomicMax(kmax) REMOVED (1024 same-address device atomics
//    serialized ~80us). Per-block max -> array -> tiny reduce kernel.
//  - fused: depth-1 register prefetch of E/S B-fragment clusters.
// b=2 h=8 n=4096 d=64 r=256 e=64, chunk=64.

typedef unsigned short ushort_t;
typedef __attribute__((ext_vector_type(8))) short bf16x8;
typedef __attribute__((ext_vector_type(4))) float f32x4;

#define KEPS 1e-4f
#define AEPS 1e-6f
#define NORMIZER 0.35355339059327373f   // 64^-0.25
#define RATIO 0.0625f                   // 256^-0.5

__device__ __forceinline__ ushort_t bf16r(float f) {   // RNE
  unsigned u = __float_as_uint(f);
  return (ushort_t)((u + 0x7fffu + ((u >> 16) & 1u)) >> 16);
}
__device__ __forceinline__ float ubf(ushort_t h) {
  return __uint_as_float((unsigned)h << 16);
}

// ---------------------------------------------------------------------------
// K0: split P into bf16 hi/lo.
__global__ __launch_bounds__(256) void pconv_kernel(
    const float* __restrict__ P, ushort_t* __restrict__ Phi,
    ushort_t* __restrict__ Plo)
{
  int idx = blockIdx.x * 1024 + threadIdx.x;
  #pragma unroll
  for (int p = 0; p < 4; ++p) {
    int i = idx + p * 256;
    float x = P[i];
    ushort_t h = bf16r(x);
    Phi[i] = h;
    Plo[i] = bf16r(x - ubf(h));
  }
}

// ---------------------------------------------------------------------------
// K1: feature map via MFMA. blocks 0..1023 -> q, 1024..2047 -> k.
// k-blocks write their dash-max to bmax[bid-1024] (plain store, no atomic).
__global__ __launch_bounds__(256, 4) void feat_mfma(
    const float* __restrict__ Q, const float* __restrict__ K,
    const ushort_t* __restrict__ Phi, const ushort_t* __restrict__ Plo,
    ushort_t* __restrict__ qp, ushort_t* __restrict__ E,
    float* __restrict__ bmax)
{
  __shared__ ushort_t Xhi[64 * 72];
  __shared__ ushort_t Xlo[64 * 72];
  __shared__ ushort_t outq[64 * 72];
  __shared__ float diagS[64];
  __shared__ float redm[4];

  int bid = blockIdx.x, tid = threadIdx.x;
  bool isK = bid >= 1024;
  const float* X = isK ? K : Q;
  size_t rowbase = (size_t)(isK ? bid - 1024 : bid) * 64;

  #pragma unroll
  for (int p = 0; p < 4; ++p) {
    int idx = tid + p * 256;
    int row = idx >> 4, c4 = idx & 15;
    float4 x = *(const float4*)&X[(rowbase + row) * 64 + c4 * 4];
    ushort4 h, l;
    h.x = bf16r(x.x); l.x = bf16r(x.x - ubf(h.x));
    h.y = bf16r(x.y); l.y = bf16r(x.y - ubf(h.y));
    h.z = bf16r(x.z); l.z = bf16r(x.z - ubf(h.z));
    h.w = bf16r(x.w); l.w = bf16r(x.w - ubf(h.w));
    *(ushort4*)&Xhi[row * 72 + c4 * 4] = h;
    *(ushort4*)&Xlo[row * 72 + c4 * 4] = l;
    float ss = x.x * x.x + x.y * x.y + x.z * x.z + x.w * x.w;
    ss += __shfl_xor(ss, 1, 64); ss += __shfl_xor(ss, 2, 64);
    ss += __shfl_xor(ss, 4, 64); ss += __shfl_xor(ss, 8, 64);
    if ((tid & 15) == 0) diagS[row] = 0.0625f * ss;
  }
  __syncthreads();

  int lane = tid & 63, wv = tid >> 6;
  int n15 = lane & 15, quad = lane >> 4;

  bf16x8 ah[2], al[2];
  #pragma unroll
  for (int ks = 0; ks < 2; ++ks) {
    int off = (16 * wv + n15) * 72 + quad * 8 + 32 * ks;
    ah[ks] = *(const bf16x8*)&Xhi[off];
    al[ks] = *(const bf16x8*)&Xlo[off];
  }

  bf16x8 nbh[2], nbl[2];
  #pragma unroll
  for (int ks = 0; ks < 2; ++ks) {
    int poff = n15 * 64 + quad * 8 + 32 * ks;
    nbh[ks] = *(const bf16x8*)&Phi[poff];
    nbl[ks] = *(const bf16x8*)&Plo[poff];
  }

  f32x4 acc[16];
  #pragma unroll
  for (int tc = 0; tc < 16; ++tc) acc[tc] = f32x4{0.f, 0.f, 0.f, 0.f};

  #pragma unroll
  for (int tc = 0; tc < 16; ++tc) {
    bf16x8 bh0 = nbh[0], bl0 = nbl[0], bh1 = nbh[1], bl1 = nbl[1];
    if (tc < 15) {
      #pragma unroll
      for (int ks = 0; ks < 2; ++ks) {
        int poff = (16 * (tc + 1) + n15) * 64 + quad * 8 + 32 * ks;
        nbh[ks] = *(const bf16x8*)&Phi[poff];
        nbl[ks] = *(const bf16x8*)&Plo[poff];
      }
    }
    f32x4 a = acc[tc];
    a = __builtin_amdgcn_mfma_f32_16x16x32_bf16(ah[0], bh0, a, 0, 0, 0);
    a = __builtin_amdgcn_mfma_f32_16x16x32_bf16(ah[0], bl0, a, 0, 0, 0);
    a = __builtin_amdgcn_mfma_f32_16x16x32_bf16(al[0], bh0, a, 0, 0, 0);
    a = __builtin_amdgcn_mfma_f32_16x16x32_bf16(ah[1], bh1, a, 0, 0, 0);
    a = __builtin_amdgcn_mfma_f32_16x16x32_bf16(ah[1], bl1, a, 0, 0, 0);
    a = __builtin_amdgcn_mfma_f32_16x16x32_bf16(al[1], bh1, a, 0, 0, 0);
    acc[tc] = a;
  }

  // C/D: row = 16*wv + quad*4 + r, col = 16*tc + n15
  float dg[4];
  #pragma unroll
  for (int r = 0; r < 4; ++r) dg[r] = diagS[16 * wv + quad * 4 + r];

  float sub[4];
  if (!isK) {
    #pragma unroll
    for (int r = 0; r < 4; ++r) {
      float mx = -3.0e38f;
      #pragma unroll
      for (int tc = 0; tc < 16; ++tc) mx = fmaxf(mx, acc[tc][r]);
      #pragma unroll
      for (int s = 1; s < 16; s <<= 1) mx = fmaxf(mx, __shfl_xor(mx, s, 64));
      sub[r] = dg[r] + NORMIZER * mx;
    }
  } else {
    float bm = -3.0e38f;
    #pragma unroll
    for (int tc = 0; tc < 16; ++tc)
      #pragma unroll
      for (int r = 0; r < 4; ++r) bm = fmaxf(bm, acc[tc][r]);
    #pragma unroll
    for (int s = 1; s < 64; s <<= 1) bm = fmaxf(bm, __shfl_xor(bm, s, 64));
    if (lane == 0) redm[wv] = bm;
    #pragma unroll
    for (int r = 0; r < 4; ++r) sub[r] = dg[r];
  }

  ushort_t* dst = (isK ? E : qp) + rowbase * 256;
  #pragma unroll
  for (int qt = 0; qt < 4; ++qt) {
    if (qt) __syncthreads();
    #pragma unroll
    for (int t4 = 0; t4 < 4; ++t4) {
      int tc = qt * 4 + t4;
      #pragma unroll
      for (int r = 0; r < 4; ++r) {
        int row = 16 * wv + quad * 4 + r;
        float ex = __expf(NORMIZER * acc[tc][r] - sub[r]);
        float val = isK ? ex : RATIO * (ex + KEPS);
        outq[row * 72 + t4 * 16 + n15] = bf16r(val);
      }
    }
    __syncthreads();
    int row = tid >> 2, c0 = (tid & 3) * 16;
    bf16x8 v0 = *(const bf16x8*)&outq[row * 72 + c0];
    bf16x8 v1 = *(const bf16x8*)&outq[row * 72 + c0 + 8];
    *(bf16x8*)&dst[row * 256 + qt * 64 + c0] = v0;
    *(bf16x8*)&dst[row * 256 + qt * 64 + c0 + 8] = v1;
  }

  if (isK && tid == 0) {
    float m4 = fmaxf(fmaxf(redm[0], redm[1]), fmaxf(redm[2], redm[3]));
    bmax[bid - 1024] = NORMIZER * m4;   // plain store, no contention
  }
}

// ---------------------------------------------------------------------------
// K1b: reduce 1024 per-block maxes -> kmax (single block).
__global__ __launch_bounds__(256) void kmax_reduce(
    const float* __restrict__ bmax, float* __restrict__ kmax)
{
  __shared__ float red[4];
  int tid = threadIdx.x;
  float m = fmaxf(fmaxf(bmax[tid], bmax[tid + 256]),
                  fmaxf(bmax[tid + 512], bmax[tid + 768]));
  #pragma unroll
  for (int s = 1; s < 64; s <<= 1) m = fmaxf(m, __shfl_xor(m, s, 64));
  if ((tid & 63) == 0) red[tid >> 6] = m;
  __syncthreads();
  if (tid == 0)
    *kmax = fmaxf(fmaxf(red[0], red[1]), fmaxf(red[2], red[3]));
}

// ---------------------------------------------------------------------------
// K2: per-chunk sums via MFMA, kmax-independent.
__global__ __launch_bounds__(256) void chunksum_mfma(
    const ushort_t* __restrict__ E, const float* __restrict__ V,
    ushort_t* __restrict__ SE, float* __restrict__ zE, float* __restrict__ SV)
{
  __shared__ ushort_t Et[256 * 72];
  __shared__ ushort_t Vt[64 * 72];
  __shared__ float red2[256];

  int bc = blockIdx.x, tid = threadIdx.x;
  size_t ebase = (size_t)bc * 16384;

  #pragma unroll
  for (int p = 0; p < 8; ++p) {
    int g = (tid + p * 256) * 8;
    int pos = g >> 8, j0 = g & 255;
    bf16x8 ev = *(const bf16x8*)&E[ebase + g];
    #pragma unroll
    for (int jj = 0; jj < 8; ++jj) {
      int j = j0 + jj;
      int pr = (pos + 8 * ((j >> 3) & 7)) & 63;
      Et[j * 72 + pr] = (ushort_t)ev[jj];
    }
  }
  float vsum = 0.f;
  #pragma unroll
  for (int p = 0; p < 16; ++p) {
    int g = tid + p * 256;
    int pos = g >> 6, e = g & 63;
    float x = V[(size_t)bc * 4096 + g];
    vsum += x;
    int pr = (pos + 8 * ((e >> 3) & 7)) & 63;
    Vt[e * 72 + pr] = bf16r(x);
  }
  red2[tid] = vsum;
  __syncthreads();
  if (tid < 64)
    SV[(size_t)bc * 64 + tid] =
        red2[tid] + red2[64 + tid] + red2[128 + tid] + red2[192 + tid];

  {
    float s = 0.f;
    #pragma unroll
    for (int m8 = 0; m8 < 8; ++m8) {
      bf16x8 r8 = *(const bf16x8*)&Et[tid * 72 + m8 * 8];
      #pragma unroll
      for (int x = 0; x < 8; ++x) s += ubf((ushort_t)r8[x]);
    }
    zE[(size_t)bc * 256 + tid] = s;
  }

  int lane = tid & 63, wv = tid >> 6;
  int n15 = lane & 15, quad = lane >> 4;

  bf16x8 aV[2];
  {
    int e = 16 * wv + n15;
    int rot = 8 * ((e >> 3) & 7);
    #pragma unroll
    for (int ks = 0; ks < 2; ++ks) {
      int pr = (quad * 8 + 32 * ks + rot) & 63;
      aV[ks] = *(const bf16x8*)&Vt[e * 72 + pr];
    }
  }

  f32x4 acc[16];
  #pragma unroll
  for (int tc = 0; tc < 16; ++tc) {
    int j = 16 * tc + n15;
    int rot = 8 * ((j >> 3) & 7);
    f32x4 a = {0.f, 0.f, 0.f, 0.f};
    #pragma unroll
    for (int ks = 0; ks < 2; ++ks) {
      int pr = (quad * 8 + 32 * ks + rot) & 63;
      bf16x8 b = *(const bf16x8*)&Et[j * 72 + pr];
      a = __builtin_amdgcn_mfma_f32_16x16x32_bf16(aV[ks], b, a, 0, 0, 0);
    }
    acc[tc] = a;
  }
  __syncthreads();

  ushort_t* outS = Et;
  #pragma unroll
  for (int tc = 0; tc < 16; ++tc)
    #pragma unroll
    for (int r = 0; r < 4; ++r) {
      int e = 16 * wv + quad * 4 + r;
      outS[e * 264 + 16 * tc + n15] = bf16r(acc[tc][r]);
    }
  __syncthreads();
  #pragma unroll
  for (int p = 0; p < 8; ++p) {
    int g = (tid + p * 256) * 8;
    int e = g >> 8, j0 = g & 255;
    bf16x8 vv = *(const bf16x8*)&outS[e * 264 + j0];
    *(bf16x8*)&SE[ebase + g] = vv;
  }
}

// ---------------------------------------------------------------------------
// K3: exclusive prefix over 64 chunks per bh, applying kp affine correction.
__global__ __launch_bounds__(256) void prefix_kernel(
    ushort_t* __restrict__ S, float* __restrict__ zE,
    const float* __restrict__ SV, const float* __restrict__ kmax)
{
  int b = blockIdx.x;
  float m = *kmax;
  float c1 = RATIO * __expf(-m);
  const float c0 = RATIO * KEPS;
  if (b < 1024) {
    int flat = b * 256 + threadIdx.x;
    int bh = flat >> 14;
    int idx = flat & 16383;
    int e = idx >> 8;
    size_t base = (size_t)bh * 1048576 + idx;
    const float* svp = SV + (size_t)bh * 4096 + e;
    float runE = 0.f, runV = 0.f;
    for (int cc = 0; cc < 64; cc += 8) {
      ushort_t t[8]; float sv[8];
      #pragma unroll
      for (int u2 = 0; u2 < 8; ++u2) {
        t[u2] = S[base + (size_t)(cc + u2) * 16384];
        sv[u2] = svp[(size_t)(cc + u2) * 64];
      }
      #pragma unroll
      for (int u2 = 0; u2 < 8; ++u2) {
        S[base + (size_t)(cc + u2) * 16384] = bf16r(c1 * runE + c0 * runV);
        runE += ubf(t[u2]);
        runV += sv[u2];
      }
    }
  } else {
    int bh = b - 1024;
    int j = threadIdx.x;
    size_t base = (size_t)bh * 16384 + j;
    float run = 0.f;
    for (int cc = 0; cc < 64; cc += 8) {
      float t[8];
      #pragma unroll
      for (int u2 = 0; u2 < 8; ++u2)
        t[u2] = zE[base + (size_t)(cc + u2) * 256];
      #pragma unroll
      for (int u2 = 0; u2 < 8; ++u2) {
        zE[base + (size_t)(cc + u2) * 256] = run;
        run += c1 * t[u2] + 64.0f * c0;
      }
    }
  }
}

// ---------------------------------------------------------------------------
// K4: fused MFMA scores + denominator + output, depth-1 B-frag prefetch.
__global__ __launch_bounds__(256) void fused_mfma(
    const ushort_t* __restrict__ qp, const ushort_t* __restrict__ E,
    const float* __restrict__ kmax, const float* __restrict__ Z,
    const ushort_t* __restrict__ S, const float* __restrict__ V,
    float* __restrict__ out)
{
  __shared__ ushort_t As[64 * 72];
  __shared__ ushort_t Vt[64 * 72];
  __shared__ float zv[256];
  __shared__ float qsumS[64];
  __shared__ float dqS[64];

  int bc = blockIdx.x, tid = threadIdx.x;
  int lane = tid & 63, wv = tid >> 6;
  int n15 = lane & 15, quad = lane >> 4;
  float m = *kmax;
  float c1 = RATIO * __expf(-m);
  const float c0 = RATIO * KEPS;
  size_t base = (size_t)bc * 16384;

  zv[tid] = Z[(size_t)bc * 256 + tid] + AEPS;
  #pragma unroll
  for (int p = 0; p < 16; ++p) {
    int idx = tid + p * 256;
    int t = idx >> 6, e = idx & 63;
    Vt[e * 72 + t] = bf16r(V[(size_t)bc * 4096 + idx]);
  }
  __syncthreads();

  bf16x8 aQ[8];
  #pragma unroll
  for (int ks = 0; ks < 8; ++ks)
    aQ[ks] = *(const bf16x8*)&qp[base + (size_t)(16 * wv + n15) * 256 + quad * 8 + 32 * ks];

  float qsum = 0.f, dq = 0.f;
  #pragma unroll
  for (int ks = 0; ks < 8; ++ks)
    #pragma unroll
    for (int j = 0; j < 8; ++j) {
      float qv = ubf((ushort_t)aQ[ks][j]);
      qsum += qv;
      dq += qv * zv[quad * 8 + 32 * ks + j];
    }
  qsum += __shfl_xor(qsum, 16, 64); qsum += __shfl_xor(qsum, 32, 64);
  dq   += __shfl_xor(dq, 16, 64);   dq   += __shfl_xor(dq, 32, 64);
  if (quad == 0) { qsumS[16 * wv + n15] = qsum; dqS[16 * wv + n15] = dq; }

  // ---- phase A: G = Qp * E^T, depth-1 prefetch ----
  bf16x8 bcur[8], bnxt[8];
  #pragma unroll
  for (int ks = 0; ks < 8; ++ks)
    bcur[ks] = *(const bf16x8*)&E[base + (size_t)n15 * 256 + quad * 8 + 32 * ks];

  float rs[4] = {0.f, 0.f, 0.f, 0.f};
  #pragma unroll
  for (int tc = 0; tc < 4; ++tc) {
    if (tc < 3) {
      #pragma unroll
      for (int ks = 0; ks < 8; ++ks)
        bnxt[ks] = *(const bf16x8*)&E[base + (size_t)(16 * (tc + 1) + n15) * 256 + quad * 8 + 32 * ks];
    }
    f32x4 g = {0.f, 0.f, 0.f, 0.f};
    #pragma unroll
    for (int ks = 0; ks < 8; ++ks)
      g = __builtin_amdgcn_mfma_f32_16x16x32_bf16(aQ[ks], bcur[ks], g, 0, 0, 0);
    #pragma unroll
    for (int r = 0; r < 4; ++r) {
      int i = 16 * wv + quad * 4 + r;
      int t = 16 * tc + n15;
      float val = (t <= i) ? (c1 * g[r] + c0 * qsumS[i]) : 0.f;
      As[i * 72 + t] = bf16r(val);
      rs[r] += val;
    }
    #pragma unroll
    for (int ks = 0; ks < 8; ++ks) bcur[ks] = bnxt[ks];
  }

  float dinv[4];
  #pragma unroll
  for (int r = 0; r < 4; ++r) {
    float v = rs[r];
    #pragma unroll
    for (int s = 1; s < 16; s <<= 1) v += __shfl_xor(v, s, 64);
    int i = 16 * wv + quad * 4 + r;
    dinv[r] = 1.f / (dqS[i] + v);
  }

  // ---- phase C: out = [Qp | A_sc] * [Sp ; Vt], depth-1 prefetch on S ----
  #pragma unroll
  for (int ks = 0; ks < 8; ++ks)
    bcur[ks] = *(const bf16x8*)&S[base + (size_t)n15 * 256 + quad * 8 + 32 * ks];

  #pragma unroll
  for (int ec = 0; ec < 4; ++ec) {
    if (ec < 3) {
      #pragma unroll
      for (int ks = 0; ks < 8; ++ks)
        bnxt[ks] = *(const bf16x8*)&S[base + (size_t)(16 * (ec + 1) + n15) * 256 + quad * 8 + 32 * ks];
    }
    f32x4 o = {0.f, 0.f, 0.f, 0.f};
    #pragma unroll
    for (int ks = 0; ks < 8; ++ks)
      o = __builtin_amdgcn_mfma_f32_16x16x32_bf16(aQ[ks], bcur[ks], o, 0, 0, 0);
    #pragma unroll
    for (int ks = 0; ks < 2; ++ks) {
      bf16x8 a2 = *(const bf16x8*)&As[(16 * wv + n15) * 72 + quad * 8 + 32 * ks];
      bf16x8 b2 = *(const bf16x8*)&Vt[(16 * ec + n15) * 72 + quad * 8 + 32 * ks];
      o = __builtin_amdgcn_mfma_f32_16x16x32_bf16(a2, b2, o, 0, 0, 0);
    }
    #pragma unroll
    for (int r = 0; r < 4; ++r) {
      int i = 16 * wv + quad * 4 + r;
      out[(size_t)bc * 4096 + (size_t)i * 64 + 16 * ec + n15] = o[r] * dinv[r];
    }
    #pragma unroll
    for (int ks = 0; ks < 8; ++ks) bcur[ks] = bnxt[ks];
  }
}

// ---------------------------------------------------------------------------
extern "C" void kernel_launch(void* const* d_in, const int* in_sizes, int n_in,
                              void* d_out, int out_size, void* d_ws, size_t ws_size,
                              hipStream_t stream)
{
  const float* q = (const float*)d_in[0];
  const float* k = (const float*)d_in[1];
  const float* v = (const float*)d_in[2];
  const float* P = (const float*)d_in[3];
  float* out = (float*)d_out;

  ushort_t* qp  = (ushort_t*)d_ws;
  ushort_t* E   = qp + 16777216;
  ushort_t* S   = E + 16777216;                 // SE then combined in place
  float*    zE  = (float*)(S + 16777216);       // 262144 floats
  float*    SV  = zE + 262144;                  // 65536 floats
  ushort_t* Phi = (ushort_t*)(SV + 65536);
  ushort_t* Plo = Phi + 16384;
  float*    bmax = (float*)(Plo + 16384);       // 1024 floats
  float*    kmax = bmax + 1024;

  pconv_kernel<<<16, 256, 0, stream>>>(P, Phi, Plo);
  feat_mfma<<<2048, 256, 0, stream>>>(q, k, Phi, Plo, qp, E, bmax);
  kmax_reduce<<<1, 256, 0, stream>>>(bmax, kmax);
  chunksum_mfma<<<1024, 256, 0, stream>>>(E, v, S, zE, SV);
  prefix_kernel<<<1040, 256, 0, stream>>>(S, zE, SV, kmax);
  fused_mfma<<<1024, 256, 0, stream>>>(qp, E, kmax, zE, S, v, out);
}

// Round 8
// 186.301 us; speedup vs baseline: 1.4985x; 1.2273x over previous
//
#include <hip/hip_runtime.h>

// Performer causal linear attention, MI355X. Round 8:
//  - feat: P staged per-quarter through LDS, single-buffered (37 KB LDS ->
//    4 blocks/CU), cooperative coalesced fill; kills per-wave 256 KB P
//    streaming through a thrashing L1. Epilogue aliases dead X tile.
// b=2 h=8 n=4096 d=64 r=256 e=64, chunk=64.

typedef unsigned short ushort_t;
typedef __attribute__((ext_vector_type(8))) short bf16x8;
typedef __attribute__((ext_vector_type(4))) float f32x4;

#define KEPS 1e-4f
#define AEPS 1e-6f
#define NORMIZER 0.35355339059327373f   // 64^-0.25
#define RATIO 0.0625f                   // 256^-0.5

__device__ __forceinline__ ushort_t bf16r(float f) {   // RNE
  unsigned u = __float_as_uint(f);
  return (ushort_t)((u + 0x7fffu + ((u >> 16) & 1u)) >> 16);
}
__device__ __forceinline__ float ubf(ushort_t h) {
  return __uint_as_float((unsigned)h << 16);
}

// ---------------------------------------------------------------------------
// K0: split P into bf16 hi/lo.
__global__ __launch_bounds__(256) void pconv_kernel(
    const float* __restrict__ P, ushort_t* __restrict__ Phi,
    ushort_t* __restrict__ Plo)
{
  int idx = blockIdx.x * 1024 + threadIdx.x;
  #pragma unroll
  for (int p = 0; p < 4; ++p) {
    int i = idx + p * 256;
    float x = P[i];
    ushort_t h = bf16r(x);
    Phi[i] = h;
    Plo[i] = bf16r(x - ubf(h));
  }
}

// ---------------------------------------------------------------------------
// K1: feature map via MFMA. blocks 0..1023 -> q, 1024..2047 -> k.
// P quarters (64 cols x 64 k, hi+lo) cooperatively staged in LDS.
__global__ __launch_bounds__(256, 4) void feat_mfma(
    const float* __restrict__ Q, const float* __restrict__ K,
    const ushort_t* __restrict__ Phi, const ushort_t* __restrict__ Plo,
    ushort_t* __restrict__ qp, ushort_t* __restrict__ E,
    float* __restrict__ bmax)
{
  __shared__ union {
    struct { ushort_t Xhi[64 * 72]; ushort_t Xlo[64 * 72]; } s;  // 18432 B
    ushort_t outb[64 * 72];   // epilogue staging, aliases Xhi (dead by then)
  } u;
  __shared__ ushort_t Pq[2][64 * 72];   // [hi/lo][col*72 + k], 18432 B
  __shared__ float diagS[64];
  __shared__ float redm[4];

  int bid = blockIdx.x, tid = threadIdx.x;
  bool isK = bid >= 1024;
  const float* X = isK ? K : Q;
  size_t rowbase = (size_t)(isK ? bid - 1024 : bid) * 64;

  // stage X -> hi/lo bf16; diag via 16-lane shuffle reduce on fp32 regs
  #pragma unroll
  for (int p = 0; p < 4; ++p) {
    int idx = tid + p * 256;
    int row = idx >> 4, c4 = idx & 15;
    float4 x = *(const float4*)&X[(rowbase + row) * 64 + c4 * 4];
    ushort4 h, l;
    h.x = bf16r(x.x); l.x = bf16r(x.x - ubf(h.x));
    h.y = bf16r(x.y); l.y = bf16r(x.y - ubf(h.y));
    h.z = bf16r(x.z); l.z = bf16r(x.z - ubf(h.z));
    h.w = bf16r(x.w); l.w = bf16r(x.w - ubf(h.w));
    *(ushort4*)&u.s.Xhi[row * 72 + c4 * 4] = h;
    *(ushort4*)&u.s.Xlo[row * 72 + c4 * 4] = l;
    float ss = x.x * x.x + x.y * x.y + x.z * x.z + x.w * x.w;
    ss += __shfl_xor(ss, 1, 64); ss += __shfl_xor(ss, 2, 64);
    ss += __shfl_xor(ss, 4, 64); ss += __shfl_xor(ss, 8, 64);
    if ((tid & 15) == 0) diagS[row] = 0.0625f * ss;
  }
  __syncthreads();

  int lane = tid & 63, wv = tid >> 6;
  int n15 = lane & 15, quad = lane >> 4;

  // A-fragments (hi/lo) — done before the q4=0 barrier, after which
  // nothing reads X again (outb may alias it in the epilogue).
  bf16x8 ah[2], al[2];
  #pragma unroll
  for (int ks = 0; ks < 2; ++ks) {
    int off = (16 * wv + n15) * 72 + quad * 8 + 32 * ks;
    ah[ks] = *(const bf16x8*)&u.s.Xhi[off];
    al[ks] = *(const bf16x8*)&u.s.Xlo[off];
  }

  f32x4 acc[16];
  #pragma unroll
  for (int tc = 0; tc < 16; ++tc) acc[tc] = f32x4{0.f, 0.f, 0.f, 0.f};

  #pragma unroll
  for (int q4 = 0; q4 < 4; ++q4) {
    if (q4) __syncthreads();   // prev-quarter reads done before overwrite
    // cooperative coalesced fill: 64 cols x 64 k, hi+lo
    #pragma unroll
    for (int t = 0; t < 2; ++t) {
      int f = tid + t * 256;           // 512 groups of 8
      int cl = f >> 3, k8 = (f & 7) * 8;
      size_t g = (size_t)(q4 * 64 + cl) * 64 + k8;
      *(bf16x8*)&Pq[0][cl * 72 + k8] = *(const bf16x8*)&Phi[g];
      *(bf16x8*)&Pq[1][cl * 72 + k8] = *(const bf16x8*)&Plo[g];
    }
    __syncthreads();
    #pragma unroll
    for (int tcl = 0; tcl < 4; ++tcl) {
      f32x4 a = acc[q4 * 4 + tcl];
      #pragma unroll
      for (int ks = 0; ks < 2; ++ks) {
        int off = (16 * tcl + n15) * 72 + quad * 8 + 32 * ks;
        bf16x8 bh = *(const bf16x8*)&Pq[0][off];
        bf16x8 bl = *(const bf16x8*)&Pq[1][off];
        a = __builtin_amdgcn_mfma_f32_16x16x32_bf16(ah[ks], bh, a, 0, 0, 0);
        a = __builtin_amdgcn_mfma_f32_16x16x32_bf16(ah[ks], bl, a, 0, 0, 0);
        a = __builtin_amdgcn_mfma_f32_16x16x32_bf16(al[ks], bh, a, 0, 0, 0);
      }
      acc[q4 * 4 + tcl] = a;
    }
  }

  // C/D: row = 16*wv + quad*4 + r, col = 16*tc + n15
  float dg[4];
  #pragma unroll
  for (int r = 0; r < 4; ++r) dg[r] = diagS[16 * wv + quad * 4 + r];

  float sub[4];
  if (!isK) {
    #pragma unroll
    for (int r = 0; r < 4; ++r) {
      float mx = -3.0e38f;
      #pragma unroll
      for (int tc = 0; tc < 16; ++tc) mx = fmaxf(mx, acc[tc][r]);
      #pragma unroll
      for (int s = 1; s < 16; s <<= 1) mx = fmaxf(mx, __shfl_xor(mx, s, 64));
      sub[r] = dg[r] + NORMIZER * mx;
    }
  } else {
    float bm = -3.0e38f;
    #pragma unroll
    for (int tc = 0; tc < 16; ++tc)
      #pragma unroll
      for (int r = 0; r < 4; ++r) bm = fmaxf(bm, acc[tc][r]);
    #pragma unroll
    for (int s = 1; s < 64; s <<= 1) bm = fmaxf(bm, __shfl_xor(bm, s, 64));
    if (lane == 0) redm[wv] = bm;
    #pragma unroll
    for (int r = 0; r < 4; ++r) sub[r] = dg[r];
  }

  // per-quarter epilogue through LDS (outb aliases dead X tile)
  ushort_t* dst = (isK ? E : qp) + rowbase * 256;
  #pragma unroll
  for (int qt = 0; qt < 4; ++qt) {
    __syncthreads();
    #pragma unroll
    for (int t4 = 0; t4 < 4; ++t4) {
      int tc = qt * 4 + t4;
      #pragma unroll
      for (int r = 0; r < 4; ++r) {
        int row = 16 * wv + quad * 4 + r;
        float ex = __expf(NORMIZER * acc[tc][r] - sub[r]);
        float val = isK ? ex : RATIO * (ex + KEPS);
        u.outb[row * 72 + t4 * 16 + n15] = bf16r(val);
      }
    }
    __syncthreads();
    int row = tid >> 2, c0 = (tid & 3) * 16;
    bf16x8 v0 = *(const bf16x8*)&u.outb[row * 72 + c0];
    bf16x8 v1 = *(const bf16x8*)&u.outb[row * 72 + c0 + 8];
    *(bf16x8*)&dst[row * 256 + qt * 64 + c0] = v0;
    *(bf16x8*)&dst[row * 256 + qt * 64 + c0 + 8] = v1;
  }

  if (isK && tid == 0) {
    float m4 = fmaxf(fmaxf(redm[0], redm[1]), fmaxf(redm[2], redm[3]));
    bmax[bid - 1024] = NORMIZER * m4;   // plain store, no contention
  }
}

// ---------------------------------------------------------------------------
// K1b: reduce 1024 per-block maxes -> kmax (single block).
__global__ __launch_bounds__(256) void kmax_reduce(
    const float* __restrict__ bmax, float* __restrict__ kmax)
{
  __shared__ float red[4];
  int tid = threadIdx.x;
  float m = fmaxf(fmaxf(bmax[tid], bmax[tid + 256]),
                  fmaxf(bmax[tid + 512], bmax[tid + 768]));
  #pragma unroll
  for (int s = 1; s < 64; s <<= 1) m = fmaxf(m, __shfl_xor(m, s, 64));
  if ((tid & 63) == 0) red[tid >> 6] = m;
  __syncthreads();
  if (tid == 0)
    *kmax = fmaxf(fmaxf(red[0], red[1]), fmaxf(red[2], red[3]));
}

// ---------------------------------------------------------------------------
// K2: per-chunk sums via MFMA, kmax-independent.
__global__ __launch_bounds__(256) void chunksum_mfma(
    const ushort_t* __restrict__ E, const float* __restrict__ V,
    ushort_t* __restrict__ SE, float* __restrict__ zE, float* __restrict__ SV)
{
  __shared__ ushort_t Et[256 * 72];
  __shared__ ushort_t Vt[64 * 72];
  __shared__ float red2[256];

  int bc = blockIdx.x, tid = threadIdx.x;
  size_t ebase = (size_t)bc * 16384;

  #pragma unroll
  for (int p = 0; p < 8; ++p) {
    int g = (tid + p * 256) * 8;
    int pos = g >> 8, j0 = g & 255;
    bf16x8 ev = *(const bf16x8*)&E[ebase + g];
    #pragma unroll
    for (int jj = 0; jj < 8; ++jj) {
      int j = j0 + jj;
      int pr = (pos + 8 * ((j >> 3) & 7)) & 63;
      Et[j * 72 + pr] = (ushort_t)ev[jj];
    }
  }
  float vsum = 0.f;
  #pragma unroll
  for (int p = 0; p < 16; ++p) {
    int g = tid + p * 256;
    int pos = g >> 6, e = g & 63;
    float x = V[(size_t)bc * 4096 + g];
    vsum += x;
    int pr = (pos + 8 * ((e >> 3) & 7)) & 63;
    Vt[e * 72 + pr] = bf16r(x);
  }
  red2[tid] = vsum;
  __syncthreads();
  if (tid < 64)
    SV[(size_t)bc * 64 + tid] =
        red2[tid] + red2[64 + tid] + red2[128 + tid] + red2[192 + tid];

  {
    float s = 0.f;
    #pragma unroll
    for (int m8 = 0; m8 < 8; ++m8) {
      bf16x8 r8 = *(const bf16x8*)&Et[tid * 72 + m8 * 8];
      #pragma unroll
      for (int x = 0; x < 8; ++x) s += ubf((ushort_t)r8[x]);
    }
    zE[(size_t)bc * 256 + tid] = s;
  }

  int lane = tid & 63, wv = tid >> 6;
  int n15 = lane & 15, quad = lane >> 4;

  bf16x8 aV[2];
  {
    int e = 16 * wv + n15;
    int rot = 8 * ((e >> 3) & 7);
    #pragma unroll
    for (int ks = 0; ks < 2; ++ks) {
      int pr = (quad * 8 + 32 * ks + rot) & 63;
      aV[ks] = *(const bf16x8*)&Vt[e * 72 + pr];
    }
  }

  f32x4 acc[16];
  #pragma unroll
  for (int tc = 0; tc < 16; ++tc) {
    int j = 16 * tc + n15;
    int rot = 8 * ((j >> 3) & 7);
    f32x4 a = {0.f, 0.f, 0.f, 0.f};
    #pragma unroll
    for (int ks = 0; ks < 2; ++ks) {
      int pr = (quad * 8 + 32 * ks + rot) & 63;
      bf16x8 b = *(const bf16x8*)&Et[j * 72 + pr];
      a = __builtin_amdgcn_mfma_f32_16x16x32_bf16(aV[ks], b, a, 0, 0, 0);
    }
    acc[tc] = a;
  }
  __syncthreads();

  ushort_t* outS = Et;
  #pragma unroll
  for (int tc = 0; tc < 16; ++tc)
    #pragma unroll
    for (int r = 0; r < 4; ++r) {
      int e = 16 * wv + quad * 4 + r;
      outS[e * 264 + 16 * tc + n15] = bf16r(acc[tc][r]);
    }
  __syncthreads();
  #pragma unroll
  for (int p = 0; p < 8; ++p) {
    int g = (tid + p * 256) * 8;
    int e = g >> 8, j0 = g & 255;
    bf16x8 vv = *(const bf16x8*)&outS[e * 264 + j0];
    *(bf16x8*)&SE[ebase + g] = vv;
  }
}

// ---------------------------------------------------------------------------
// K3: exclusive prefix over 64 chunks per bh, applying kp affine correction.
__global__ __launch_bounds__(256) void prefix_kernel(
    ushort_t* __restrict__ S, float* __restrict__ zE,
    const float* __restrict__ SV, const float* __restrict__ kmax)
{
  int b = blockIdx.x;
  float m = *kmax;
  float c1 = RATIO * __expf(-m);
  const float c0 = RATIO * KEPS;
  if (b < 1024) {
    int flat = b * 256 + threadIdx.x;
    int bh = flat >> 14;
    int idx = flat & 16383;
    int e = idx >> 8;
    size_t base = (size_t)bh * 1048576 + idx;
    const float* svp = SV + (size_t)bh * 4096 + e;
    float runE = 0.f, runV = 0.f;
    for (int cc = 0; cc < 64; cc += 8) {
      ushort_t t[8]; float sv[8];
      #pragma unroll
      for (int u2 = 0; u2 < 8; ++u2) {
        t[u2] = S[base + (size_t)(cc + u2) * 16384];
        sv[u2] = svp[(size_t)(cc + u2) * 64];
      }
      #pragma unroll
      for (int u2 = 0; u2 < 8; ++u2) {
        S[base + (size_t)(cc + u2) * 16384] = bf16r(c1 * runE + c0 * runV);
        runE += ubf(t[u2]);
        runV += sv[u2];
      }
    }
  } else {
    int bh = b - 1024;
    int j = threadIdx.x;
    size_t base = (size_t)bh * 16384 + j;
    float run = 0.f;
    for (int cc = 0; cc < 64; cc += 8) {
      float t[8];
      #pragma unroll
      for (int u2 = 0; u2 < 8; ++u2)
        t[u2] = zE[base + (size_t)(cc + u2) * 256];
      #pragma unroll
      for (int u2 = 0; u2 < 8; ++u2) {
        zE[base + (size_t)(cc + u2) * 256] = run;
        run += c1 * t[u2] + 64.0f * c0;
      }
    }
  }
}

// ---------------------------------------------------------------------------
// K4: fused MFMA scores + denominator + output, depth-1 B-frag prefetch.
__global__ __launch_bounds__(256) void fused_mfma(
    const ushort_t* __restrict__ qp, const ushort_t* __restrict__ E,
    const float* __restrict__ kmax, const float* __restrict__ Z,
    const ushort_t* __restrict__ S, const float* __restrict__ V,
    float* __restrict__ out)
{
  __shared__ ushort_t As[64 * 72];
  __shared__ ushort_t Vt[64 * 72];
  __shared__ float zv[256];
  __shared__ float qsumS[64];
  __shared__ float dqS[64];

  int bc = blockIdx.x, tid = threadIdx.x;
  int lane = tid & 63, wv = tid >> 6;
  int n15 = lane & 15, quad = lane >> 4;
  float m = *kmax;
  float c1 = RATIO * __expf(-m);
  const float c0 = RATIO * KEPS;
  size_t base = (size_t)bc * 16384;

  zv[tid] = Z[(size_t)bc * 256 + tid] + AEPS;
  #pragma unroll
  for (int p = 0; p < 16; ++p) {
    int idx = tid + p * 256;
    int t = idx >> 6, e = idx & 63;
    Vt[e * 72 + t] = bf16r(V[(size_t)bc * 4096 + idx]);
  }
  __syncthreads();

  bf16x8 aQ[8];
  #pragma unroll
  for (int ks = 0; ks < 8; ++ks)
    aQ[ks] = *(const bf16x8*)&qp[base + (size_t)(16 * wv + n15) * 256 + quad * 8 + 32 * ks];

  float qsum = 0.f, dq = 0.f;
  #pragma unroll
  for (int ks = 0; ks < 8; ++ks)
    #pragma unroll
    for (int j = 0; j < 8; ++j) {
      float qv = ubf((ushort_t)aQ[ks][j]);
      qsum += qv;
      dq += qv * zv[quad * 8 + 32 * ks + j];
    }
  qsum += __shfl_xor(qsum, 16, 64); qsum += __shfl_xor(qsum, 32, 64);
  dq   += __shfl_xor(dq, 16, 64);   dq   += __shfl_xor(dq, 32, 64);
  if (quad == 0) { qsumS[16 * wv + n15] = qsum; dqS[16 * wv + n15] = dq; }

  // ---- phase A: G = Qp * E^T, depth-1 prefetch ----
  bf16x8 bcur[8], bnxt[8];
  #pragma unroll
  for (int ks = 0; ks < 8; ++ks)
    bcur[ks] = *(const bf16x8*)&E[base + (size_t)n15 * 256 + quad * 8 + 32 * ks];

  float rs[4] = {0.f, 0.f, 0.f, 0.f};
  #pragma unroll
  for (int tc = 0; tc < 4; ++tc) {
    if (tc < 3) {
      #pragma unroll
      for (int ks = 0; ks < 8; ++ks)
        bnxt[ks] = *(const bf16x8*)&E[base + (size_t)(16 * (tc + 1) + n15) * 256 + quad * 8 + 32 * ks];
    }
    f32x4 g = {0.f, 0.f, 0.f, 0.f};
    #pragma unroll
    for (int ks = 0; ks < 8; ++ks)
      g = __builtin_amdgcn_mfma_f32_16x16x32_bf16(aQ[ks], bcur[ks], g, 0, 0, 0);
    #pragma unroll
    for (int r = 0; r < 4; ++r) {
      int i = 16 * wv + quad * 4 + r;
      int t = 16 * tc + n15;
      float val = (t <= i) ? (c1 * g[r] + c0 * qsumS[i]) : 0.f;
      As[i * 72 + t] = bf16r(val);
      rs[r] += val;
    }
    #pragma unroll
    for (int ks = 0; ks < 8; ++ks) bcur[ks] = bnxt[ks];
  }

  float dinv[4];
  #pragma unroll
  for (int r = 0; r < 4; ++r) {
    float v = rs[r];
    #pragma unroll
    for (int s = 1; s < 16; s <<= 1) v += __shfl_xor(v, s, 64);
    int i = 16 * wv + quad * 4 + r;
    dinv[r] = 1.f / (dqS[i] + v);
  }

  // ---- phase C: out = [Qp | A_sc] * [Sp ; Vt], depth-1 prefetch on S ----
  #pragma unroll
  for (int ks = 0; ks < 8; ++ks)
    bcur[ks] = *(const bf16x8*)&S[base + (size_t)n15 * 256 + quad * 8 + 32 * ks];

  #pragma unroll
  for (int ec = 0; ec < 4; ++ec) {
    if (ec < 3) {
      #pragma unroll
      for (int ks = 0; ks < 8; ++ks)
        bnxt[ks] = *(const bf16x8*)&S[base + (size_t)(16 * (ec + 1) + n15) * 256 + quad * 8 + 32 * ks];
    }
    f32x4 o = {0.f, 0.f, 0.f, 0.f};
    #pragma unroll
    for (int ks = 0; ks < 8; ++ks)
      o = __builtin_amdgcn_mfma_f32_16x16x32_bf16(aQ[ks], bcur[ks], o, 0, 0, 0);
    #pragma unroll
    for (int ks = 0; ks < 2; ++ks) {
      bf16x8 a2 = *(const bf16x8*)&As[(16 * wv + n15) * 72 + quad * 8 + 32 * ks];
      bf16x8 b2 = *(const bf16x8*)&Vt[(16 * ec + n15) * 72 + quad * 8 + 32 * ks];
      o = __builtin_amdgcn_mfma_f32_16x16x32_bf16(a2, b2, o, 0, 0, 0);
    }
    #pragma unroll
    for (int r = 0; r < 4; ++r) {
      int i = 16 * wv + quad * 4 + r;
      out[(size_t)bc * 4096 + (size_t)i * 64 + 16 * ec + n15] = o[r] * dinv[r];
    }
    #pragma unroll
    for (int ks = 0; ks < 8; ++ks) bcur[ks] = bnxt[ks];
  }
}

// ---------------------------------------------------------------------------
extern "C" void kernel_launch(void* const* d_in, const int* in_sizes, int n_in,
                              void* d_out, int out_size, void* d_ws, size_t ws_size,
                              hipStream_t stream)
{
  const float* q = (const float*)d_in[0];
  const float* k = (const float*)d_in[1];
  const float* v = (const float*)d_in[2];
  const float* P = (const float*)d_in[3];
  float* out = (float*)d_out;

  ushort_t* qp  = (ushort_t*)d_ws;
  ushort_t* E   = qp + 16777216;
  ushort_t* S   = E + 16777216;                 // SE then combined in place
  float*    zE  = (float*)(S + 16777216);       // 262144 floats
  float*    SV  = zE + 262144;                  // 65536 floats
  ushort_t* Phi = (ushort_t*)(SV + 65536);
  ushort_t* Plo = Phi + 16384;
  float*    bmax = (float*)(Plo + 16384);       // 1024 floats
  float*    kmax = bmax + 1024;

  pconv_kernel<<<16, 256, 0, stream>>>(P, Phi, Plo);
  feat_mfma<<<2048, 256, 0, stream>>>(q, k, Phi, Plo, qp, E, bmax);
  kmax_reduce<<<1, 256, 0, stream>>>(bmax, kmax);
  chunksum_mfma<<<1024, 256, 0, stream>>>(E, v, S, zE, SV);
  prefix_kernel<<<1040, 256, 0, stream>>>(S, zE, SV, kmax);
  fused_mfma<<<1024, 256, 0, stream>>>(qp, E, kmax, zE, S, v, out);
}